// Round 12
// baseline (600.984 us; speedup 1.0000x reference)
//
#include <hip/hip_runtime.h>
#include <stdint.h>

// Problem constants (from reference)
#define NN      5000
#define NB      8
#define TSTEPS  256
#define NDELAY  15
#define NW      157          // uint32 words covering 5000 presyn bits
#define NIPAD   5120         // padded neuron dim (columns of maskT2)
#define RW      160          // ring row stride in words (640 B)
#define IPB     256          // threads per block
#define BPB     20           // blocks per batch
#define NBLK    (NB*BPB)     // 160 blocks -> 1 per CU, co-resident
#define RING_SLOTS 32
#define CH      4            // chunk length (64 chunks)
#define NCHUNK  (TSTEPS/CH)  // 64
#define BARSTRIDE 16         // ints between chunk counters (64B apart)

// Workspace layout (bytes)
#define MASK_BYTES (RW*NIPAD*4)          // 3,276,800
#define BAR_OFF    MASK_BYTES
#define BAR_BYTES  (64*BARSTRIDE*4)      // 4,096 (64 chunk counters)
#define RING_OFF   (BAR_OFF + BAR_BYTES)
#define RING_BYTES (RING_SLOTS*NB*RW*4)  // 163,840
#define ZERO_BYTES (RING_OFF + RING_BYTES)

// ---------------------------------------------------------------------------
// Kernel 1: bit-pack connectivity, word-major-transposed:
//   maskT2[w*NIPAD + i] bit (j&31), w=j>>5, set iff W[i,j] != 0.
// ---------------------------------------------------------------------------
__global__ void _Brunel_build_mask(const float* __restrict__ W,
                                   uint32_t* __restrict__ maskT2)
{
    int j = blockIdx.x * blockDim.x + threadIdx.x;   // presyn 0..5119
    int i = blockIdx.y;                              // postsyn row 0..4999
    int lane = threadIdx.x & 63;
    bool nz = false;
    if (j < NN) nz = (W[(size_t)i * NN + j] != 0.0f);
    unsigned long long m = __ballot(nz);
    if ((lane & 31) == 0 && j < NN) {
        uint32_t wd = (lane == 0) ? (uint32_t)m : (uint32_t)(m >> 32);
        maskT2[(size_t)(j >> 5) * NIPAD + i] = wd;
    }
}

// ---------------------------------------------------------------------------
// Kernel 2: persistent SNN sim.
//  Round-12 change vs round 11: spike words NEVER touch LDS. Lane l holds
//  word 64g+l (g=0..2) of each step in VGPRs (12 regs, loaded from the ring
//  one chunk ahead -- T14 skeleton kept); inner loop broadcasts them via
//  v_readlane (VALU pipe) and ANDs with the per-lane mask word from LDS.
//  LDS instructions drop 780 -> 156 per CU per chunk (was the saturated pipe:
//  624 of 780 b128 reads were wave-uniform broadcasts re-read 4x).
//  Sync scheme (per-chunk barc counters, sc0sc1 coherence-point ring,
//  vmcnt(0)+barrier arrive) = round 11 verbatim.
// ---------------------------------------------------------------------------
__global__ void __launch_bounds__(IPB, 1) _Brunel_persist(
    const float* __restrict__ ext,
    const uint32_t* __restrict__ maskT2,
    uint32_t* __restrict__ ring,
    int* __restrict__ barc,
    float* __restrict__ out_spk,
    float* __restrict__ out_vs)
{
    const int tx   = threadIdx.x;
    const int bb   = blockIdx.x;
    const int b    = bb / BPB;
    const int i    = (bb % BPB) * IPB + tx;
    const bool act = (i < NN);
    const int lane = tx & 63;

    __shared__ __align__(16) uint32_t s_mask[IPB][156];   // 159,744 B
    __shared__ uint32_t s_mask156[IPB];                   //   1,024 B
                                                          // = 160,768 B

    // ---- one-time: mask row -> LDS (own row only; coalesced over tx) ----
    for (int w = 0; w < NW; ++w) {
        uint32_t mv = maskT2[(size_t)w * NIPAD + i];      // pad cols are 0
        if (w < 156) s_mask[tx][w] = mv; else s_mask156[tx] = mv;
    }
    __syncthreads();

    float v = 0.0f;

    // spike-word registers: c<k><g> current chunk, n<k><g> next chunk.
    // lane l holds word 64g+l (g=2 clamped to 156; lanes>28 unused there).
    uint32_t cA0=0,cA1=0,cA2=0, cB0=0,cB1=0,cB2=0,
             cC0=0,cC1=0,cC2=0, cD0=0,cD1=0,cD2=0;
    uint32_t nA0=0,nA1=0,nA2=0, nB0=0,nB1=0,nB2=0,
             nC0=0,nC1=0,nC2=0, nD0=0,nD1=0,nD2=0;

    const int wg0 = lane;                       // g=0 word
    const int wg1 = 64 + lane;                  // g=1 word
    const int wg2 = (128 + lane > 156) ? 156 : 128 + lane;  // g=2 (clamped)

    for (int t0 = 0, m = 0; t0 < TSTEPS; t0 += CH, ++m) {
        // ---- roll pipeline: cur <- next (chunk m's words, loaded at m-1) ----
        cA0=nA0; cA1=nA1; cA2=nA2; cB0=nB0; cB1=nB1; cB2=nB2;
        cC0=nC0; cC1=nC1; cC2=nC2; cD0=nD0; cD1=nD1; cD2=nD2;

        // ---- prefetch external inputs for this chunk ----
        float x0 = 0.f, x1 = 0.f, x2 = 0.f, x3 = 0.f;
        if (act) {
            const float* e0 = ext + ((size_t)t0 * NB + b) * NN + i;
            const size_t st = (size_t)NB * NN;
            x0 = e0[0]; x1 = e0[st]; x2 = e0[2 * st]; x3 = e0[3 * st];
        }

        // ---- poll chunk m-2 (writers of chunk m+1's slots), issue loads ----
        if (m >= 2 && m < NCHUNK - 1) {
            if (tx == 0) {
                const int* c3 = barc + (size_t)(m - 2) * BARSTRIDE;
                while (__hip_atomic_load(c3, __ATOMIC_RELAXED,
                                         __HIP_MEMORY_SCOPE_AGENT) < NBLK)
                    __builtin_amdgcn_s_sleep(2);
            }
            __syncthreads();                 // loads must not pass the poll
            const int ts0 = (t0 + CH) - NDELAY;   // chunk m+1's base ts
#define RLD(KOFF, WRD) __hip_atomic_load(                                     \
        &ring[((size_t)(((ts0 + (KOFF)) & (RING_SLOTS - 1)) * NB + b)) * RW   \
              + (WRD)], __ATOMIC_RELAXED, __HIP_MEMORY_SCOPE_AGENT)
            nA0 = RLD(0, wg0); nA1 = RLD(0, wg1); nA2 = RLD(0, wg2);
            nB0 = RLD(1, wg0); nB1 = RLD(1, wg1); nB2 = RLD(1, wg2);
            nC0 = RLD(2, wg0); nC1 = RLD(2, wg1); nC2 = RLD(2, wg2);
            nD0 = RLD(3, wg0); nD1 = RLD(3, wg1); nD2 = RLD(3, wg2);
#undef RLD
        }

        // ---- synapse counts: mask from LDS, spikes via v_readlane ----
        int cE0 = 0, cE1 = 0, cE2 = 0, cE3 = 0;
        int cI0 = 0, cI1 = 0, cI2 = 0, cI3 = 0;
        const uint32_t* __restrict__ mrow = s_mask[tx];

#define PROC(MW, W, LN, SA, SB, SC, SD)                                       \
        { uint32_t u0 = (uint32_t)__builtin_amdgcn_readlane((int)(SA), (LN)); \
          uint32_t u1 = (uint32_t)__builtin_amdgcn_readlane((int)(SB), (LN)); \
          uint32_t u2 = (uint32_t)__builtin_amdgcn_readlane((int)(SC), (LN)); \
          uint32_t u3 = (uint32_t)__builtin_amdgcn_readlane((int)(SD), (LN)); \
          if ((W) < 125) {                                                    \
              cE0 += __popc((MW) & u0); cE1 += __popc((MW) & u1);             \
              cE2 += __popc((MW) & u2); cE3 += __popc((MW) & u3);             \
          } else {                                                            \
              cI0 += __popc((MW) & u0); cI1 += __popc((MW) & u1);             \
              cI2 += __popc((MW) & u2); cI3 += __popc((MW) & u3);             \
          } }

#define GRP(G, L, SA, SB, SC, SD)                                             \
        { uint4 m4 = *(const uint4*)(mrow + 64 * (G) + 4 * (L));              \
          PROC(m4.x, 64*(G)+4*(L)+0, 4*(L)+0, SA, SB, SC, SD)                 \
          PROC(m4.y, 64*(G)+4*(L)+1, 4*(L)+1, SA, SB, SC, SD)                 \
          PROC(m4.z, 64*(G)+4*(L)+2, 4*(L)+2, SA, SB, SC, SD)                 \
          PROC(m4.w, 64*(G)+4*(L)+3, 4*(L)+3, SA, SB, SC, SD) }

        // g=0: words 0..63 (all excitatory)
        GRP(0, 0,cA0,cB0,cC0,cD0) GRP(0, 1,cA0,cB0,cC0,cD0)
        GRP(0, 2,cA0,cB0,cC0,cD0) GRP(0, 3,cA0,cB0,cC0,cD0)
        GRP(0, 4,cA0,cB0,cC0,cD0) GRP(0, 5,cA0,cB0,cC0,cD0)
        GRP(0, 6,cA0,cB0,cC0,cD0) GRP(0, 7,cA0,cB0,cC0,cD0)
        GRP(0, 8,cA0,cB0,cC0,cD0) GRP(0, 9,cA0,cB0,cC0,cD0)
        GRP(0,10,cA0,cB0,cC0,cD0) GRP(0,11,cA0,cB0,cC0,cD0)
        GRP(0,12,cA0,cB0,cC0,cD0) GRP(0,13,cA0,cB0,cC0,cD0)
        GRP(0,14,cA0,cB0,cC0,cD0) GRP(0,15,cA0,cB0,cC0,cD0)
        // g=1: words 64..127 (124 exc boundary inside L=15, compile-time)
        GRP(1, 0,cA1,cB1,cC1,cD1) GRP(1, 1,cA1,cB1,cC1,cD1)
        GRP(1, 2,cA1,cB1,cC1,cD1) GRP(1, 3,cA1,cB1,cC1,cD1)
        GRP(1, 4,cA1,cB1,cC1,cD1) GRP(1, 5,cA1,cB1,cC1,cD1)
        GRP(1, 6,cA1,cB1,cC1,cD1) GRP(1, 7,cA1,cB1,cC1,cD1)
        GRP(1, 8,cA1,cB1,cC1,cD1) GRP(1, 9,cA1,cB1,cC1,cD1)
        GRP(1,10,cA1,cB1,cC1,cD1) GRP(1,11,cA1,cB1,cC1,cD1)
        GRP(1,12,cA1,cB1,cC1,cD1) GRP(1,13,cA1,cB1,cC1,cD1)
        GRP(1,14,cA1,cB1,cC1,cD1) GRP(1,15,cA1,cB1,cC1,cD1)
        // g=2: words 128..155 (all inhibitory)
        GRP(2, 0,cA2,cB2,cC2,cD2) GRP(2, 1,cA2,cB2,cC2,cD2)
        GRP(2, 2,cA2,cB2,cC2,cD2) GRP(2, 3,cA2,cB2,cC2,cD2)
        GRP(2, 4,cA2,cB2,cC2,cD2) GRP(2, 5,cA2,cB2,cC2,cD2)
        GRP(2, 6,cA2,cB2,cC2,cD2)
        {   // word 156 (inhibitory): lane 28 of the g=2 regs
            uint32_t mL = s_mask156[tx];
            cI0 += __popc(mL & (uint32_t)__builtin_amdgcn_readlane((int)cA2, 28));
            cI1 += __popc(mL & (uint32_t)__builtin_amdgcn_readlane((int)cB2, 28));
            cI2 += __popc(mL & (uint32_t)__builtin_amdgcn_readlane((int)cC2, 28));
            cI3 += __popc(mL & (uint32_t)__builtin_amdgcn_readlane((int)cD2, 28));
        }
#undef GRP
#undef PROC

        // ---- 4 sequential neuron updates + ring publish ----
#define BRUNEL_STEP(kk, xk)                                                   \
        {                                                                     \
            const int t = t0 + kk;                                            \
            float cur = 0.1f * (float)cE##kk - 0.5f * (float)cI##kk;          \
            v = v * 0.95f + (cur + xk);                                       \
            bool s = act && (v >= 1.0f);                                      \
            float sflag = s ? 1.0f : 0.0f;                                    \
            float vout  = s ? 0.0f : v;                                       \
            if (act) {                                                        \
                size_t o = ((size_t)t * NB + b) * NN + i;                     \
                out_spk[o] = sflag;                                           \
                out_vs[o]  = vout;                                            \
            }                                                                 \
            v = vout;                                                         \
            unsigned long long bm = __ballot(s);                              \
            if ((lane & 31) == 0 && act) {                                    \
                uint32_t wd = (lane == 0) ? (uint32_t)bm : (uint32_t)(bm >> 32); \
                __hip_atomic_store(                                           \
                    &ring[((size_t)(t & (RING_SLOTS - 1)) * NB + b) * RW + (i >> 5)], \
                    wd, __ATOMIC_RELAXED, __HIP_MEMORY_SCOPE_AGENT);          \
            }                                                                 \
        }
        BRUNEL_STEP(0, x0)
        BRUNEL_STEP(1, x1)
        BRUNEL_STEP(2, x2)
        BRUNEL_STEP(3, x3)
#undef BRUNEL_STEP

        // ---- arrive: per-wave store drain, block barrier, relaxed add ----
        asm volatile("s_waitcnt vmcnt(0)" ::: "memory");  // ring stores at LLC
        __syncthreads();
        if (tx == 0)
            __hip_atomic_fetch_add(barc + (size_t)m * BARSTRIDE, 1,
                                   __ATOMIC_RELAXED, __HIP_MEMORY_SCOPE_AGENT);
    }
}

// ---------------------------------------------------------------------------
extern "C" void kernel_launch(void* const* d_in, const int* in_sizes, int n_in,
                              void* d_out, int out_size, void* d_ws, size_t ws_size,
                              hipStream_t stream)
{
    const float* ext = (const float*)d_in[0];   // [T,B,N] fp32
    const float* W   = (const float*)d_in[1];   // [N,N]   fp32

    float* out_spk = (float*)d_out;                          // [T,B,N]
    float* out_vs  = out_spk + (size_t)TSTEPS * NB * NN;     // [T,B,N]

    uint8_t*  ws   = (uint8_t*)d_ws;
    uint32_t* mask = (uint32_t*)(ws);
    int*      barc = (int*)(ws + BAR_OFF);
    uint32_t* ring = (uint32_t*)(ws + RING_OFF);

    // zero mask (pad columns must read 0) + per-chunk counters + ring
    hipMemsetAsync(ws, 0, ZERO_BYTES, stream);

    dim3 gmask(NIPAD / IPB, NN);   // (20, 5000)
    _Brunel_build_mask<<<gmask, IPB, 0, stream>>>(W, mask);

    _Brunel_persist<<<NBLK, IPB, 0, stream>>>(ext, mask, ring, barc,
                                              out_spk, out_vs);
}

// Round 13
// 542.493 us; speedup vs baseline: 1.1078x; 1.1078x over previous
//
#include <hip/hip_runtime.h>
#include <stdint.h>

// Problem constants (from reference)
#define NN      5000
#define NB      8
#define TSTEPS  256
#define NDELAY  15
#define NW      157          // uint32 words covering 5000 presyn bits
#define NIPAD   5120         // padded neuron dim (columns of maskT2)
#define RW      160          // ring row stride in words (640 B, 16B-aligned)
#define IPB     256          // threads per block
#define BPB     20           // blocks per batch
#define NBLK    (NB*BPB)     // 160 blocks -> 1 per CU, co-resident
#define CH      4            // chunk length (64 chunks)
#define NCHUNK  (TSTEPS/CH)  // 64
#define BARSTRIDE 16         // ints between chunk counters (64B apart)
#define RING_DEPTH 256       // WRITE-ONCE ring: slot = step + 15 (no reuse)

// Workspace layout (bytes)
#define MASK_BYTES (NW*NIPAD*4)              // 3,215,360
#define BAR_OFF    MASK_BYTES
#define BAR_BYTES  (64*BARSTRIDE*4)          // 4,096
#define RING_OFF   (BAR_OFF + BAR_BYTES)     // 3,219,456 (16B-aligned)
#define RING_BYTES (RING_DEPTH*NB*RW*4)      // 1,310,720
#define ZERO_BYTES (RING_OFF + RING_BYTES)   // 4,530,176 total

// ---------------------------------------------------------------------------
// Kernel 1: bit-pack connectivity, word-major-transposed:
//   maskT2[w*NIPAD + i] bit (j&31), w=j>>5, set iff W[i,j] != 0.
// ---------------------------------------------------------------------------
__global__ void _Brunel_build_mask(const float* __restrict__ W,
                                   uint32_t* __restrict__ maskT2)
{
    int j = blockIdx.x * blockDim.x + threadIdx.x;   // presyn 0..5119
    int i = blockIdx.y;                              // postsyn row 0..4999
    int lane = threadIdx.x & 63;
    bool nz = false;
    if (j < NN) nz = (W[(size_t)i * NN + j] != 0.0f);
    unsigned long long m = __ballot(nz);
    if ((lane & 31) == 0 && j < NN) {
        uint32_t wd = (lane == 0) ? (uint32_t)m : (uint32_t)(m >> 32);
        maskT2[(size_t)(j >> 5) * NIPAD + i] = wd;
    }
}

// ---------------------------------------------------------------------------
// Kernel 2: persistent SNN sim.
//  Round-13 change vs R11/R12: spike words come from WAVE-UNIFORM CACHED
//  global loads of a WRITE-ONCE ring (slot = step+15, 256 slots, no reuse
//  within a launch -> a cached line is never rewritten -> normal caching is
//  safe; dispatch-boundary invalidation covers replays; slots 0..14 are
//  memset zero and serve ts<0). Uniform load -> operand replicated across
//  lanes -> v_and uses it directly: 3 VALU/word/step (floor), zero
//  broadcast ops (R12's overhead), zero spike LDS traffic (R11's 250us).
//  Mask stays in LDS (per-lane ds_read_b128, 39/wave/chunk).
//  Sync (per-chunk barc, sc0sc1 ring WRITES, vmcnt(0)+barrier arrive,
//  poll barc[m-3]) unchanged from the proven rounds.
// ---------------------------------------------------------------------------
__global__ void __launch_bounds__(IPB, 1) _Brunel_persist(
    const float* __restrict__ ext,
    const uint32_t* __restrict__ maskT2,
    uint32_t* __restrict__ ring,
    int* __restrict__ barc,
    float* __restrict__ out_spk,
    float* __restrict__ out_vs)
{
    const int tx   = threadIdx.x;
    const int bb   = blockIdx.x;
    const int b    = bb / BPB;
    const int i    = (bb % BPB) * IPB + tx;
    const bool act = (i < NN);
    const int lane = tx & 63;

    __shared__ __align__(16) uint32_t s_mask[IPB][156];   // 159,744 B
    __shared__ uint32_t s_mask156[IPB];                   //   1,024 B

    // ---- one-time: mask row -> LDS (own row only; coalesced over tx) ----
    for (int w = 0; w < NW; ++w) {
        uint32_t mv = maskT2[(size_t)w * NIPAD + i];      // pad cols are 0
        if (w < 156) s_mask[tx][w] = mv; else s_mask156[tx] = mv;
    }
    __syncthreads();

    float v = 0.0f;

    for (int t0 = 0, m = 0; t0 < TSTEPS; t0 += CH, ++m) {
        // ---- prefetch external inputs for this chunk ----
        float x0 = 0.f, x1 = 0.f, x2 = 0.f, x3 = 0.f;
        if (act) {
            const float* e0 = ext + ((size_t)t0 * NB + b) * NN + i;
            const size_t st = (size_t)NB * NN;
            x0 = e0[0]; x1 = e0[st]; x2 = e0[2 * st]; x3 = e0[3 * st];
        }

        // ---- gate: all blocks finished chunk m-3 (writers of our slots) ----
        if (m >= 3) {
            if (tx == 0) {
                const int* c3 = barc + (size_t)(m - 3) * BARSTRIDE;
                while (__hip_atomic_load(c3, __ATOMIC_RELAXED,
                                         __HIP_MEMORY_SCOPE_AGENT) < NBLK)
                    __builtin_amdgcn_s_sleep(2);
            }
            __syncthreads();     // no reads may pass the gate
        }

        // ---- spike rows for this chunk: slots t0..t0+3 (write-once ring) ----
        // slots 0..14 are memset zero => chunks 0..2 read zeros, no branch
        const uint4* __restrict__ s0 =
            (const uint4*)(ring + ((size_t)(t0 + 0) * NB + b) * RW);
        const uint4* __restrict__ s1 =
            (const uint4*)(ring + ((size_t)(t0 + 1) * NB + b) * RW);
        const uint4* __restrict__ s2 =
            (const uint4*)(ring + ((size_t)(t0 + 2) * NB + b) * RW);
        const uint4* __restrict__ s3 =
            (const uint4*)(ring + ((size_t)(t0 + 3) * NB + b) * RW);

        // ---- synapse counts: mask (LDS, per-lane) AND spikes (uniform) ----
        int cE0 = 0, cE1 = 0, cE2 = 0, cE3 = 0;
        int cI0 = 0, cI1 = 0, cI2 = 0, cI3 = 0;
        const uint32_t* __restrict__ mrow = s_mask[tx];

#pragma unroll 4                       // bounded: no full-unroll spill
        for (int c = 0; c < 31; ++c) { // words 0..123: all excitatory
            uint4 m4 = *(const uint4*)(mrow + 4 * c);
            uint4 a0 = s0[c], a1 = s1[c], a2 = s2[c], a3 = s3[c];
            cE0 += __popc(m4.x & a0.x) + __popc(m4.y & a0.y)
                 + __popc(m4.z & a0.z) + __popc(m4.w & a0.w);
            cE1 += __popc(m4.x & a1.x) + __popc(m4.y & a1.y)
                 + __popc(m4.z & a1.z) + __popc(m4.w & a1.w);
            cE2 += __popc(m4.x & a2.x) + __popc(m4.y & a2.y)
                 + __popc(m4.z & a2.z) + __popc(m4.w & a2.w);
            cE3 += __popc(m4.x & a3.x) + __popc(m4.y & a3.y)
                 + __popc(m4.z & a3.z) + __popc(m4.w & a3.w);
        }
        {   // c = 31: word 124 excitatory, words 125..127 inhibitory
            uint4 m4 = *(const uint4*)(mrow + 124);
            uint4 a0 = s0[31], a1 = s1[31], a2 = s2[31], a3 = s3[31];
            cE0 += __popc(m4.x & a0.x);
            cI0 += __popc(m4.y & a0.y) + __popc(m4.z & a0.z) + __popc(m4.w & a0.w);
            cE1 += __popc(m4.x & a1.x);
            cI1 += __popc(m4.y & a1.y) + __popc(m4.z & a1.z) + __popc(m4.w & a1.w);
            cE2 += __popc(m4.x & a2.x);
            cI2 += __popc(m4.y & a2.y) + __popc(m4.z & a2.z) + __popc(m4.w & a2.w);
            cE3 += __popc(m4.x & a3.x);
            cI3 += __popc(m4.y & a3.y) + __popc(m4.z & a3.z) + __popc(m4.w & a3.w);
        }
#pragma unroll 4
        for (int c = 32; c < 39; ++c) { // words 128..155: all inhibitory
            uint4 m4 = *(const uint4*)(mrow + 4 * c);
            uint4 a0 = s0[c], a1 = s1[c], a2 = s2[c], a3 = s3[c];
            cI0 += __popc(m4.x & a0.x) + __popc(m4.y & a0.y)
                 + __popc(m4.z & a0.z) + __popc(m4.w & a0.w);
            cI1 += __popc(m4.x & a1.x) + __popc(m4.y & a1.y)
                 + __popc(m4.z & a1.z) + __popc(m4.w & a1.w);
            cI2 += __popc(m4.x & a2.x) + __popc(m4.y & a2.y)
                 + __popc(m4.z & a2.z) + __popc(m4.w & a2.w);
            cI3 += __popc(m4.x & a3.x) + __popc(m4.y & a3.y)
                 + __popc(m4.z & a3.z) + __popc(m4.w & a3.w);
        }
        {   // word 156 (inhibitory): direct uniform dword loads
            uint32_t mL = s_mask156[tx];
            cI0 += __popc(mL & ((const uint32_t*)s0)[156]);
            cI1 += __popc(mL & ((const uint32_t*)s1)[156]);
            cI2 += __popc(mL & ((const uint32_t*)s2)[156]);
            cI3 += __popc(mL & ((const uint32_t*)s3)[156]);
        }

        // ---- 4 sequential neuron updates + write-once ring publish ----
#define BRUNEL_STEP(kk, xk)                                                   \
        {                                                                     \
            const int t = t0 + kk;                                            \
            float cur = 0.1f * (float)cE##kk - 0.5f * (float)cI##kk;          \
            v = v * 0.95f + (cur + xk);                                       \
            bool s = act && (v >= 1.0f);                                      \
            float sflag = s ? 1.0f : 0.0f;                                    \
            float vout  = s ? 0.0f : v;                                       \
            if (act) {                                                        \
                size_t o = ((size_t)t * NB + b) * NN + i;                     \
                out_spk[o] = sflag;                                           \
                out_vs[o]  = vout;                                            \
            }                                                                 \
            v = vout;                                                         \
            unsigned long long bm = __ballot(s);                              \
            if ((lane & 31) == 0 && act && t <= TSTEPS - 1 - NDELAY) {        \
                uint32_t wd = (lane == 0) ? (uint32_t)bm : (uint32_t)(bm >> 32); \
                __hip_atomic_store(                                           \
                    &ring[((size_t)(t + NDELAY) * NB + b) * RW + (i >> 5)],   \
                    wd, __ATOMIC_RELAXED, __HIP_MEMORY_SCOPE_AGENT);          \
            }                                                                 \
        }
        BRUNEL_STEP(0, x0)
        BRUNEL_STEP(1, x1)
        BRUNEL_STEP(2, x2)
        BRUNEL_STEP(3, x3)
#undef BRUNEL_STEP

        // ---- arrive: per-wave store drain, block barrier, relaxed add ----
        asm volatile("s_waitcnt vmcnt(0)" ::: "memory");  // ring stores at LLC
        __syncthreads();
        if (tx == 0)
            __hip_atomic_fetch_add(barc + (size_t)m * BARSTRIDE, 1,
                                   __ATOMIC_RELAXED, __HIP_MEMORY_SCOPE_AGENT);
    }
}

// ---------------------------------------------------------------------------
extern "C" void kernel_launch(void* const* d_in, const int* in_sizes, int n_in,
                              void* d_out, int out_size, void* d_ws, size_t ws_size,
                              hipStream_t stream)
{
    const float* ext = (const float*)d_in[0];   // [T,B,N] fp32
    const float* W   = (const float*)d_in[1];   // [N,N]   fp32

    float* out_spk = (float*)d_out;                          // [T,B,N]
    float* out_vs  = out_spk + (size_t)TSTEPS * NB * NN;     // [T,B,N]

    uint8_t*  ws   = (uint8_t*)d_ws;
    uint32_t* mask = (uint32_t*)(ws);
    int*      barc = (int*)(ws + BAR_OFF);
    uint32_t* ring = (uint32_t*)(ws + RING_OFF);

    // zero mask (pad cols) + per-chunk counters + whole write-once ring
    // (slots 0..14 MUST be zero: they serve ts<0 reads)
    hipMemsetAsync(ws, 0, ZERO_BYTES, stream);

    dim3 gmask(NIPAD / IPB, NN);   // (20, 5000)
    _Brunel_build_mask<<<gmask, IPB, 0, stream>>>(W, mask);

    _Brunel_persist<<<NBLK, IPB, 0, stream>>>(ext, mask, ring, barc,
                                              out_spk, out_vs);
}